// Round 1
// baseline (1876.957 us; speedup 1.0000x reference)
//
#include <hip/hip_runtime.h>
#include <hip/hip_bf16.h>

// Problem constants (fixed by the reference)
#define M 2048
#define N 131072
#define D 256

// Tiling
#define QT 128          // query tile (rows)
#define NT 128          // vector tile (cols)
#define DC 32           // depth chunk staged in LDS
#define QTP (QT + 4)    // +4 float pad: keeps ds_read_b128 16B-aligned, breaks
#define NTP (NT + 4)    //   the worst staging-write bank conflicts (8-way -> 4-way)

__device__ __forceinline__ unsigned long long shfl_xor_u64(unsigned long long x, int mask, int width) {
    unsigned lo = (unsigned)x;
    unsigned hi = (unsigned)(x >> 32);
    lo = (unsigned)__shfl_xor((int)lo, mask, width);
    hi = (unsigned)__shfl_xor((int)hi, mask, width);
    return ((unsigned long long)hi << 32) | lo;
}

// Kernel A: v_sq[n] = sum_d v[n][d]^2  (wave-per-vector), plus key init.
__global__ __launch_bounds__(256) void vsq_init_kernel(const float* __restrict__ v,
                                                       float* __restrict__ vsq,
                                                       unsigned long long* __restrict__ keys) {
    const int tid  = threadIdx.x;
    const int w    = tid >> 6;        // wave in block (0..3)
    const int lane = tid & 63;
    const int n    = blockIdx.x * 4 + w;

    const float4 a = *(const float4*)(v + (size_t)n * D + lane * 4);
    float s = a.x * a.x + a.y * a.y + a.z * a.z + a.w * a.w;
#pragma unroll
    for (int off = 32; off; off >>= 1) s += __shfl_xor(s, off, 64);
    if (lane == 0) vsq[n] = s;

    if (blockIdx.x == 0) {
        for (int i = tid; i < M; i += 256) keys[i] = ~0ull;
    }
}

// Kernel B: 128x128 tile of score = v_sq[n] - 2*q.v ; per-query argmin via
// packed-key atomicMin. Each thread computes an 8x8 sub-tile.
__global__ __launch_bounds__(256) void dist_argmin_kernel(const float* __restrict__ q,
                                                          const float* __restrict__ v,
                                                          const float* __restrict__ vsq,
                                                          unsigned long long* __restrict__ keys) {
    __shared__ float qs[DC][QTP];
    __shared__ float vs[DC][NTP];

    const int tid = threadIdx.x;
    const int tx  = tid & 15;         // vector-col group
    const int ty  = tid >> 4;         // query-row group
    const int tx4 = tx * 4;
    const int ty4 = ty * 4;

    const int qb0 = blockIdx.y * QT;  // 16 block-rows
    const int vb0 = blockIdx.x * NT;  // 1024 block-cols

    float acc[8][8];
#pragma unroll
    for (int i = 0; i < 8; ++i)
#pragma unroll
        for (int j = 0; j < 8; ++j) acc[i][j] = 0.0f;

    // staging mapping: 8 threads per row, 4 row-passes
    const int sj    = tid & 7;        // float4 slot within the 32-wide d-chunk
    const int rbase = tid >> 3;       // 0..31

    for (int dc = 0; dc < D; dc += DC) {
        if (dc) __syncthreads();      // protect previous chunk's reads
#pragma unroll
        for (int rr = 0; rr < 4; ++rr) {
            const int r = rbase + rr * 32;
            const float4 a = *(const float4*)(q + (size_t)(qb0 + r) * D + dc + sj * 4);
            qs[sj * 4 + 0][r] = a.x;
            qs[sj * 4 + 1][r] = a.y;
            qs[sj * 4 + 2][r] = a.z;
            qs[sj * 4 + 3][r] = a.w;
            const float4 b = *(const float4*)(v + (size_t)(vb0 + r) * D + dc + sj * 4);
            vs[sj * 4 + 0][r] = b.x;
            vs[sj * 4 + 1][r] = b.y;
            vs[sj * 4 + 2][r] = b.z;
            vs[sj * 4 + 3][r] = b.w;
        }
        __syncthreads();

#pragma unroll
        for (int d = 0; d < DC; ++d) {
            float qv[8], vv[8];
            *(float4*)&qv[0] = *(const float4*)&qs[d][ty4];
            *(float4*)&qv[4] = *(const float4*)&qs[d][64 + ty4];
            *(float4*)&vv[0] = *(const float4*)&vs[d][tx4];
            *(float4*)&vv[4] = *(const float4*)&vs[d][64 + tx4];
#pragma unroll
            for (int i = 0; i < 8; ++i)
#pragma unroll
                for (int j = 0; j < 8; ++j)
                    acc[i][j] = fmaf(qv[i], vv[j], acc[i][j]);
        }
    }

    // Epilogue: score = fma(-2, cross, v_sq); pack (monotonic_bits, idx); min.
    float vsqr[8];
    int   cols[8];
#pragma unroll
    for (int j = 0; j < 8; ++j) {
        const int c = (j < 4) ? (tx4 + j) : (64 + tx4 + (j - 4));
        cols[j] = vb0 + c;
        vsqr[j] = vsq[vb0 + c];
    }

#pragma unroll
    for (int i = 0; i < 8; ++i) {
        const int qrow = (i < 4) ? (ty4 + i) : (64 + ty4 + (i - 4));
        unsigned long long best = ~0ull;
#pragma unroll
        for (int j = 0; j < 8; ++j) {
            const float score = fmaf(-2.0f, acc[i][j], vsqr[j]);
            unsigned u = __float_as_uint(score);
            u = (u & 0x80000000u) ? ~u : (u | 0x80000000u);   // monotonic total order
            const unsigned long long key = ((unsigned long long)u << 32) | (unsigned)cols[j];
            best = best < key ? best : key;
        }
#pragma unroll
        for (int off = 8; off; off >>= 1) {
            const unsigned long long o = shfl_xor_u64(best, off, 16);
            best = best < o ? best : o;
        }
        if (tx == 0) atomicMin(&keys[qb0 + qrow], best);
    }
}

// Kernel C: extract index from packed key.
__global__ __launch_bounds__(256) void extract_kernel(const unsigned long long* __restrict__ keys,
                                                      int* __restrict__ out) {
    const int i = blockIdx.x * 256 + threadIdx.x;
    if (i < M) out[i] = (int)(unsigned)(keys[i] & 0xFFFFFFFFull);
}

extern "C" void kernel_launch(void* const* d_in, const int* in_sizes, int n_in,
                              void* d_out, int out_size, void* d_ws, size_t ws_size,
                              hipStream_t stream) {
    const float* q = (const float*)d_in[0];   // [M, D] fp32
    const float* v = (const float*)d_in[1];   // [N, D] fp32
    int* out = (int*)d_out;                   // [M] int32 indices

    // workspace layout: [0, N) floats = v_sq ; then M ull keys
    float* vsq = (float*)d_ws;
    unsigned long long* keys = (unsigned long long*)((char*)d_ws + (size_t)N * sizeof(float));

    vsq_init_kernel<<<N / 4, 256, 0, stream>>>(v, vsq, keys);

    dim3 grid(N / NT, M / QT);   // (1024, 16)
    dist_argmin_kernel<<<grid, 256, 0, stream>>>(q, v, vsq, keys);

    extract_kernel<<<(M + 255) / 256, 256, 0, stream>>>(keys, out);
}

// Round 2
// 839.398 us; speedup vs baseline: 2.2361x; 2.2361x over previous
//
#include <hip/hip_runtime.h>
#include <hip/hip_bf16.h>

#define M 2048
#define N 131072
#define D 256

#define QT 128
#define NT 128
#define KC 32
#define NBLK (N / NT)   // 1024

typedef __attribute__((ext_vector_type(8))) short short8;   // 8 bf16 (4 VGPRs)
typedef __attribute__((ext_vector_type(4))) float f32x4;    // MFMA acc

__device__ __forceinline__ short bf16_rne(float f) {
    unsigned u = __float_as_uint(f);
    u += 0x7FFFu + ((u >> 16) & 1u);      // round-to-nearest-even
    return (short)(u >> 16);
}
__device__ __forceinline__ float bf16_to_f(short h) {
    return __uint_as_float(((unsigned)(unsigned short)h) << 16);
}
__device__ __forceinline__ unsigned long long pack_key(float score, unsigned idx) {
    unsigned u = __float_as_uint(score);
    u = (u & 0x80000000u) ? ~u : (u | 0x80000000u);   // monotonic total order
    return ((unsigned long long)u << 32) | idx;
}
__device__ __forceinline__ unsigned long long shfl_xor_u64_w16(unsigned long long x, int mask) {
    unsigned lo = (unsigned)x, hi = (unsigned)(x >> 32);
    lo = (unsigned)__shfl_xor((int)lo, mask, 16);
    hi = (unsigned)__shfl_xor((int)hi, mask, 16);
    return ((unsigned long long)hi << 32) | lo;
}

// ---------------- Kernel A: vsq + key init ----------------
__global__ __launch_bounds__(256) void vsq_init_kernel(const float* __restrict__ v,
                                                       float* __restrict__ vsq,
                                                       unsigned long long* __restrict__ keys) {
    const int tid  = threadIdx.x;
    const int w    = tid >> 6;
    const int lane = tid & 63;
    const int n    = blockIdx.x * 4 + w;

    const float4 a = *(const float4*)(v + (size_t)n * D + lane * 4);
    float s = a.x * a.x + a.y * a.y + a.z * a.z + a.w * a.w;
#pragma unroll
    for (int off = 32; off; off >>= 1) s += __shfl_xor(s, off, 64);
    if (lane == 0) vsq[n] = s;

    if (blockIdx.x == 0) {
        for (int i = tid; i < 2 * M; i += 256) keys[i] = ~0ull;   // keys1 | keys2
    }
}

// ---------------- Kernel B: bf16x2 MFMA GEMM + block-best top-2 insert ----------------
// hi/lo staging: convert 8 consecutive fp32 to bf16 hi+lo, write as b128s.
__device__ __forceinline__ void stage8(const float* __restrict__ g, short* ldsHi, short* ldsLo, int off) {
    const float4 f0 = *(const float4*)g;
    const float4 f1 = *(const float4*)(g + 4);
    float tmp[8] __attribute__((aligned(16)));
    *(float4*)&tmp[0] = f0;
    *(float4*)&tmp[4] = f1;
    short8 hi, lo;
#pragma unroll
    for (int e = 0; e < 8; ++e) {
        const short h = bf16_rne(tmp[e]);
        hi[e] = h;
        lo[e] = bf16_rne(tmp[e] - bf16_to_f(h));
    }
    *(short8*)(ldsHi + off) = hi;
    *(short8*)(ldsLo + off) = lo;
}

__global__ __launch_bounds__(256) void dist_argmin_kernel(const float* __restrict__ q,
                                                          const float* __restrict__ v,
                                                          const float* __restrict__ vsq,
                                                          unsigned long long* __restrict__ keys1,
                                                          unsigned long long* __restrict__ keys2) {
    // bf16 tiles, row-major [row][KC], 64B rows: conflict-minimal for b128 r/w
    __shared__ __align__(16) short sQhi[QT * KC];
    __shared__ __align__(16) short sQlo[QT * KC];
    __shared__ __align__(16) short sVhi[NT * KC];
    __shared__ __align__(16) short sVlo[NT * KC];
    __shared__ unsigned long long red[QT][2];

    const int tid  = threadIdx.x;
    const int lane = tid & 63;
    const int w    = tid >> 6;
    const int wq   = (w >> 1) * 64;   // wave q-offset in tile
    const int wn   = (w & 1) * 64;    // wave n-offset in tile
    const int tx   = lane & 15;
    const int quad = lane >> 4;

    const int qb0 = blockIdx.y * QT;
    const int vb0 = blockIdx.x * NT;

    f32x4 acc[4][4];
#pragma unroll
    for (int i = 0; i < 4; ++i)
#pragma unroll
        for (int j = 0; j < 4; ++j) acc[i][j] = (f32x4){0.f, 0.f, 0.f, 0.f};

    // staging mapping: group g of 8 floats -> row = g>>2, col0 = (g&3)*8
    const int r0 = tid >> 2;
    const int c0 = (tid & 3) * 8;
    const int r1 = (tid + 256) >> 2;
    const int c1 = ((tid + 256) & 3) * 8;

    for (int dc = 0; dc < D; dc += KC) {
        __syncthreads();
        stage8(q + (size_t)(qb0 + r0) * D + dc + c0, sQhi, sQlo, r0 * KC + c0);
        stage8(q + (size_t)(qb0 + r1) * D + dc + c1, sQhi, sQlo, r1 * KC + c1);
        stage8(v + (size_t)(vb0 + r0) * D + dc + c0, sVhi, sVlo, r0 * KC + c0);
        stage8(v + (size_t)(vb0 + r1) * D + dc + c1, sVhi, sVlo, r1 * KC + c1);
        __syncthreads();

        short8 ahi[4], alo[4];
#pragma unroll
        for (int mt = 0; mt < 4; ++mt) {
            const int off = (wq + mt * 16 + tx) * KC + quad * 8;
            ahi[mt] = *(const short8*)(sQhi + off);
            alo[mt] = *(const short8*)(sQlo + off);
        }
#pragma unroll
        for (int nt = 0; nt < 4; ++nt) {
            const int off = (wn + nt * 16 + tx) * KC + quad * 8;
            const short8 bhi = *(const short8*)(sVhi + off);
            const short8 blo = *(const short8*)(sVlo + off);
#pragma unroll
            for (int mt = 0; mt < 4; ++mt) {
                acc[mt][nt] = __builtin_amdgcn_mfma_f32_16x16x32_bf16(ahi[mt], blo, acc[mt][nt], 0, 0, 0);
                acc[mt][nt] = __builtin_amdgcn_mfma_f32_16x16x32_bf16(alo[mt], bhi, acc[mt][nt], 0, 0, 0);
                acc[mt][nt] = __builtin_amdgcn_mfma_f32_16x16x32_bf16(ahi[mt], bhi, acc[mt][nt], 0, 0, 0);
            }
        }
    }

    // Epilogue: per-q-row block-min of (vsq - 2*cross), then top-2 atomic insert.
    float vsqr[4];
#pragma unroll
    for (int nt = 0; nt < 4; ++nt) vsqr[nt] = vsq[vb0 + wn + nt * 16 + tx];

#pragma unroll
    for (int mt = 0; mt < 4; ++mt) {
#pragma unroll
        for (int r = 0; r < 4; ++r) {
            const int q_local = wq + mt * 16 + quad * 4 + r;
            unsigned long long best = ~0ull;
#pragma unroll
            for (int nt = 0; nt < 4; ++nt) {
                const float score = fmaf(-2.0f, acc[mt][nt][r], vsqr[nt]);
                const unsigned idx = (unsigned)(vb0 + wn + nt * 16 + tx);
                const unsigned long long key = pack_key(score, idx);
                best = best < key ? best : key;
            }
#pragma unroll
            for (int off = 8; off; off >>= 1) {
                const unsigned long long o = shfl_xor_u64_w16(best, off);
                best = best < o ? best : o;
            }
            if (tx == 0) red[q_local][wn >> 6] = best;
        }
    }
    __syncthreads();

    if (tid < QT) {
        const unsigned long long k0 = red[tid][0];
        const unsigned long long k1 = red[tid][1];
        const unsigned long long x  = k0 < k1 ? k0 : k1;   // block-best for this q
        const int qg = qb0 + tid;
        const unsigned long long old = atomicMin(&keys1[qg], x);
        const unsigned long long loser = (x < old) ? old : x;
        if (loser != ~0ull) atomicMin(&keys2[qg], loser);
    }
}

// ---------------- Kernel C: exact fp32 rescore of approx top-2 ----------------
__global__ __launch_bounds__(256) void rescore_kernel(const float* __restrict__ q,
                                                      const float* __restrict__ v,
                                                      const unsigned long long* __restrict__ keys1,
                                                      const unsigned long long* __restrict__ keys2,
                                                      int* __restrict__ out) {
    const int qi   = blockIdx.x * 4 + (threadIdx.x >> 6);
    const int lane = threadIdx.x & 63;

    const float4 qv = *(const float4*)(q + (size_t)qi * D + lane * 4);
    unsigned long long best = ~0ull;

    unsigned long long cand[2];
    cand[0] = keys1[qi];
    cand[1] = keys2[qi];

#pragma unroll
    for (int c = 0; c < 2; ++c) {
        if (cand[c] == ~0ull) continue;
        const unsigned idx = (unsigned)cand[c];
        const float4 vv = *(const float4*)(v + (size_t)idx * D + lane * 4);
        float s1 = vv.x * vv.x + vv.y * vv.y + vv.z * vv.z + vv.w * vv.w;   // ||v||^2 part
        float s2 = qv.x * vv.x + qv.y * vv.y + qv.z * vv.z + qv.w * vv.w;   // q.v part
#pragma unroll
        for (int off = 32; off; off >>= 1) {
            s1 += __shfl_xor(s1, off, 64);
            s2 += __shfl_xor(s2, off, 64);
        }
        const float dist = fmaf(-2.0f, s2, s1);   // exact fp32 score (sans ||q||^2)
        const unsigned long long key = pack_key(dist, idx);
        best = best < key ? best : key;
    }
    if (lane == 0) out[qi] = (int)(unsigned)(best & 0xFFFFFFFFull);
}

extern "C" void kernel_launch(void* const* d_in, const int* in_sizes, int n_in,
                              void* d_out, int out_size, void* d_ws, size_t ws_size,
                              hipStream_t stream) {
    const float* q = (const float*)d_in[0];
    const float* v = (const float*)d_in[1];
    int* out = (int*)d_out;

    float* vsq = (float*)d_ws;                                                  // N floats
    unsigned long long* keys = (unsigned long long*)((char*)d_ws + (size_t)N * sizeof(float));
    unsigned long long* keys1 = keys;                                           // M
    unsigned long long* keys2 = keys + M;                                       // M

    vsq_init_kernel<<<N / 4, 256, 0, stream>>>(v, vsq, keys);

    dim3 grid(NBLK, M / QT);   // (1024, 16), x fastest -> V streamed per q-pass (L3 reuse)
    dist_argmin_kernel<<<grid, 256, 0, stream>>>(q, v, vsq, keys1, keys2);

    rescore_kernel<<<M / 4, 256, 0, stream>>>(q, v, keys1, keys2, out);
}

// Round 3
// 798.773 us; speedup vs baseline: 2.3498x; 1.0509x over previous
//
#include <hip/hip_runtime.h>
#include <hip/hip_bf16.h>

#define M 2048
#define N 131072
#define D 256

#define QT 128
#define NT 128
#define KC 32

typedef __attribute__((ext_vector_type(8))) short short8;   // 8 bf16 (4 VGPRs)
typedef __attribute__((ext_vector_type(4))) float f32x4;    // MFMA acc
typedef unsigned long long ull;

__device__ __forceinline__ short bf16_rne(float f) {
    unsigned u = __float_as_uint(f);
    u += 0x7FFFu + ((u >> 16) & 1u);      // round-to-nearest-even
    return (short)(u >> 16);
}
__device__ __forceinline__ float bf16_to_f(short h) {
    return __uint_as_float(((unsigned)(unsigned short)h) << 16);
}
__device__ __forceinline__ ull pack_key(float score, unsigned idx) {
    unsigned u = __float_as_uint(score);
    u = (u & 0x80000000u) ? ~u : (u | 0x80000000u);   // monotonic total order
    return ((ull)u << 32) | idx;
}
__device__ __forceinline__ ull shfl_xor_u64_w16(ull x, int mask) {
    unsigned lo = (unsigned)x, hi = (unsigned)(x >> 32);
    lo = (unsigned)__shfl_xor((int)lo, mask, 16);
    hi = (unsigned)__shfl_xor((int)hi, mask, 16);
    return ((ull)hi << 32) | lo;
}
// async global->LDS, 16B per lane; lds ptr must be wave-uniform, lane i lands at +16*i
__device__ __forceinline__ void async16(const void* g, void* l) {
    __builtin_amdgcn_global_load_lds((const __attribute__((address_space(1))) void*)g,
                                     (__attribute__((address_space(3))) void*)l, 16, 0, 0);
}

// ---------------- Kernel A1: V -> (hi, lo) bf16 split + vsq (V read once) ----------------
__global__ __launch_bounds__(256) void convert_v_kernel(const float* __restrict__ v,
                                                        short* __restrict__ vhi,
                                                        short* __restrict__ vlo,
                                                        float* __restrict__ vsq) {
    const size_t t = (size_t)blockIdx.x * 256 + threadIdx.x;   // N*D/8 threads
    const float* src = v + t * 8;
    float tmp[8] __attribute__((aligned(16)));
    *(float4*)&tmp[0] = *(const float4*)src;
    *(float4*)&tmp[4] = *(const float4*)(src + 4);
    short8 hi, lo;
    float s = 0.f;
#pragma unroll
    for (int e = 0; e < 8; ++e) {
        const short h = bf16_rne(tmp[e]);
        hi[e] = h;
        lo[e] = bf16_rne(tmp[e] - bf16_to_f(h));
        s += tmp[e] * tmp[e];
    }
    *(short8*)(vhi + t * 8) = hi;
    *(short8*)(vlo + t * 8) = lo;
#pragma unroll
    for (int off = 16; off; off >>= 1) s += __shfl_xor(s, off, 32);   // 32 threads per row
    if ((threadIdx.x & 31) == 0) vsq[t >> 5] = s;
}

// ---------------- Kernel A2: Q -> (hi, lo) + key init ----------------
__global__ __launch_bounds__(256) void convert_q_kernel(const float* __restrict__ q,
                                                        short* __restrict__ qhi,
                                                        short* __restrict__ qlo,
                                                        ull* __restrict__ keys) {
    const size_t t = (size_t)blockIdx.x * 256 + threadIdx.x;   // M*D/8 threads
    const float* src = q + t * 8;
    float tmp[8] __attribute__((aligned(16)));
    *(float4*)&tmp[0] = *(const float4*)src;
    *(float4*)&tmp[4] = *(const float4*)(src + 4);
    short8 hi, lo;
#pragma unroll
    for (int e = 0; e < 8; ++e) {
        const short h = bf16_rne(tmp[e]);
        hi[e] = h;
        lo[e] = bf16_rne(tmp[e] - bf16_to_f(h));
    }
    *(short8*)(qhi + t * 8) = hi;
    *(short8*)(qlo + t * 8) = lo;
    if (blockIdx.x == 0) {
        for (int i = threadIdx.x; i < 2 * M; i += 256) keys[i] = ~0ull;
    }
}

// ---------------- Kernel B (fast): pure-bf16 MFMA GEMM, DMA staging ----------------
__global__ __launch_bounds__(256) void dist_argmin_fast(const short* __restrict__ qhi,
                                                        const short* __restrict__ qlo,
                                                        const short* __restrict__ vhi,
                                                        const short* __restrict__ vlo,
                                                        const float* __restrict__ vsq,
                                                        ull* __restrict__ keys1,
                                                        ull* __restrict__ keys2) {
    __shared__ __align__(16) short sQhi[QT * KC];
    __shared__ __align__(16) short sQlo[QT * KC];
    __shared__ __align__(16) short sVhi[NT * KC];
    __shared__ __align__(16) short sVlo[NT * KC];
    __shared__ ull red[QT][2];

    const int tid  = threadIdx.x;
    const int lane = tid & 63;
    const int w    = tid >> 6;
    const int wq   = (w >> 1) * 64;
    const int wn   = (w & 1) * 64;
    const int tx   = lane & 15;
    const int quad = lane >> 4;

    const int qb0 = blockIdx.y * QT;
    const int vb0 = blockIdx.x * NT;

    f32x4 acc[4][4];
#pragma unroll
    for (int i = 0; i < 4; ++i)
#pragma unroll
        for (int j = 0; j < 4; ++j) acc[i][j] = (f32x4){0.f, 0.f, 0.f, 0.f};

    // DMA staging: wave w stages rows [w*32, w*32+32) of each tile; lane i -> row w*32+(i>>2),
    // element col (i&3)*8. LDS dest (wave-uniform) + lane*16 == [row][KC] row-major order.
    const int  srow   = w * 32 + (lane >> 2);
    const int  scol   = (lane & 3) * 8;
    const size_t qg   = (size_t)(qb0 + srow) * D + scol;
    const size_t vg   = (size_t)(vb0 + srow) * D + scol;
    const int  l0     = (w * 32) * KC;          // lds short-offsets (wave-uniform)
    const int  l1     = (w * 32 + 16) * KC;

    for (int dc = 0; dc < D; dc += KC) {
        __syncthreads();                         // prior chunk's frag reads done
        async16(qhi + qg + dc,          sQhi + l0);
        async16(qhi + qg + 16 * D + dc, sQhi + l1);
        async16(qlo + qg + dc,          sQlo + l0);
        async16(qlo + qg + 16 * D + dc, sQlo + l1);
        async16(vhi + vg + dc,          sVhi + l0);
        async16(vhi + vg + 16 * D + dc, sVhi + l1);
        async16(vlo + vg + dc,          sVlo + l0);
        async16(vlo + vg + 16 * D + dc, sVlo + l1);
        __syncthreads();                         // DMA drained (vmcnt(0) before barrier)

        short8 ahi[4], alo[4];
#pragma unroll
        for (int mt = 0; mt < 4; ++mt) {
            const int off = (wq + mt * 16 + tx) * KC + quad * 8;
            ahi[mt] = *(const short8*)(sQhi + off);
            alo[mt] = *(const short8*)(sQlo + off);
        }
#pragma unroll
        for (int nt = 0; nt < 4; ++nt) {
            const int off = (wn + nt * 16 + tx) * KC + quad * 8;
            const short8 bhi = *(const short8*)(sVhi + off);
            const short8 blo = *(const short8*)(sVlo + off);
#pragma unroll
            for (int mt = 0; mt < 4; ++mt) {
                acc[mt][nt] = __builtin_amdgcn_mfma_f32_16x16x32_bf16(ahi[mt], blo, acc[mt][nt], 0, 0, 0);
                acc[mt][nt] = __builtin_amdgcn_mfma_f32_16x16x32_bf16(alo[mt], bhi, acc[mt][nt], 0, 0, 0);
                acc[mt][nt] = __builtin_amdgcn_mfma_f32_16x16x32_bf16(ahi[mt], bhi, acc[mt][nt], 0, 0, 0);
            }
        }
    }

    float vsqr[4];
#pragma unroll
    for (int nt = 0; nt < 4; ++nt) vsqr[nt] = vsq[vb0 + wn + nt * 16 + tx];

#pragma unroll
    for (int mt = 0; mt < 4; ++mt) {
#pragma unroll
        for (int r = 0; r < 4; ++r) {
            const int q_local = wq + mt * 16 + quad * 4 + r;
            ull best = ~0ull;
#pragma unroll
            for (int nt = 0; nt < 4; ++nt) {
                const float score = fmaf(-2.0f, acc[mt][nt][r], vsqr[nt]);
                const unsigned idx = (unsigned)(vb0 + wn + nt * 16 + tx);
                const ull key = pack_key(score, idx);
                best = best < key ? best : key;
            }
#pragma unroll
            for (int off = 8; off; off >>= 1) {
                const ull o = shfl_xor_u64_w16(best, off);
                best = best < o ? best : o;
            }
            if (tx == 0) red[q_local][wn >> 6] = best;
        }
    }
    __syncthreads();

    if (tid < QT) {
        const ull k0 = red[tid][0];
        const ull k1 = red[tid][1];
        const ull x  = k0 < k1 ? k0 : k1;
        const int qg_ = qb0 + tid;
        const ull old = atomicMin(&keys1[qg_], x);
        const ull loser = (x < old) ? old : x;
        if (loser != ~0ull) atomicMin(&keys2[qg_], loser);
    }
}

// ---------------- Fallback kernels (round-2 path, used only if ws too small) ----------------
__global__ __launch_bounds__(256) void vsq_init_kernel(const float* __restrict__ v,
                                                       float* __restrict__ vsq,
                                                       ull* __restrict__ keys) {
    const int tid  = threadIdx.x;
    const int w    = tid >> 6;
    const int lane = tid & 63;
    const int n    = blockIdx.x * 4 + w;
    const float4 a = *(const float4*)(v + (size_t)n * D + lane * 4);
    float s = a.x * a.x + a.y * a.y + a.z * a.z + a.w * a.w;
#pragma unroll
    for (int off = 32; off; off >>= 1) s += __shfl_xor(s, off, 64);
    if (lane == 0) vsq[n] = s;
    if (blockIdx.x == 0) {
        for (int i = tid; i < 2 * M; i += 256) keys[i] = ~0ull;
    }
}

__device__ __forceinline__ void stage8(const float* __restrict__ g, short* ldsHi, short* ldsLo, int off) {
    const float4 f0 = *(const float4*)g;
    const float4 f1 = *(const float4*)(g + 4);
    float tmp[8] __attribute__((aligned(16)));
    *(float4*)&tmp[0] = f0;
    *(float4*)&tmp[4] = f1;
    short8 hi, lo;
#pragma unroll
    for (int e = 0; e < 8; ++e) {
        const short h = bf16_rne(tmp[e]);
        hi[e] = h;
        lo[e] = bf16_rne(tmp[e] - bf16_to_f(h));
    }
    *(short8*)(ldsHi + off) = hi;
    *(short8*)(ldsLo + off) = lo;
}

__global__ __launch_bounds__(256) void dist_argmin_conv(const float* __restrict__ q,
                                                        const float* __restrict__ v,
                                                        const float* __restrict__ vsq,
                                                        ull* __restrict__ keys1,
                                                        ull* __restrict__ keys2) {
    __shared__ __align__(16) short sQhi[QT * KC];
    __shared__ __align__(16) short sQlo[QT * KC];
    __shared__ __align__(16) short sVhi[NT * KC];
    __shared__ __align__(16) short sVlo[NT * KC];
    __shared__ ull red[QT][2];

    const int tid  = threadIdx.x;
    const int lane = tid & 63;
    const int w    = tid >> 6;
    const int wq   = (w >> 1) * 64;
    const int wn   = (w & 1) * 64;
    const int tx   = lane & 15;
    const int quad = lane >> 4;
    const int qb0 = blockIdx.y * QT;
    const int vb0 = blockIdx.x * NT;

    f32x4 acc[4][4];
#pragma unroll
    for (int i = 0; i < 4; ++i)
#pragma unroll
        for (int j = 0; j < 4; ++j) acc[i][j] = (f32x4){0.f, 0.f, 0.f, 0.f};

    const int r0 = tid >> 2;
    const int c0 = (tid & 3) * 8;
    const int r1 = (tid + 256) >> 2;
    const int c1 = ((tid + 256) & 3) * 8;

    for (int dc = 0; dc < D; dc += KC) {
        __syncthreads();
        stage8(q + (size_t)(qb0 + r0) * D + dc + c0, sQhi, sQlo, r0 * KC + c0);
        stage8(q + (size_t)(qb0 + r1) * D + dc + c1, sQhi, sQlo, r1 * KC + c1);
        stage8(v + (size_t)(vb0 + r0) * D + dc + c0, sVhi, sVlo, r0 * KC + c0);
        stage8(v + (size_t)(vb0 + r1) * D + dc + c1, sVhi, sVlo, r1 * KC + c1);
        __syncthreads();

        short8 ahi[4], alo[4];
#pragma unroll
        for (int mt = 0; mt < 4; ++mt) {
            const int off = (wq + mt * 16 + tx) * KC + quad * 8;
            ahi[mt] = *(const short8*)(sQhi + off);
            alo[mt] = *(const short8*)(sQlo + off);
        }
#pragma unroll
        for (int nt = 0; nt < 4; ++nt) {
            const int off = (wn + nt * 16 + tx) * KC + quad * 8;
            const short8 bhi = *(const short8*)(sVhi + off);
            const short8 blo = *(const short8*)(sVlo + off);
#pragma unroll
            for (int mt = 0; mt < 4; ++mt) {
                acc[mt][nt] = __builtin_amdgcn_mfma_f32_16x16x32_bf16(ahi[mt], blo, acc[mt][nt], 0, 0, 0);
                acc[mt][nt] = __builtin_amdgcn_mfma_f32_16x16x32_bf16(alo[mt], bhi, acc[mt][nt], 0, 0, 0);
                acc[mt][nt] = __builtin_amdgcn_mfma_f32_16x16x32_bf16(ahi[mt], bhi, acc[mt][nt], 0, 0, 0);
            }
        }
    }

    float vsqr[4];
#pragma unroll
    for (int nt = 0; nt < 4; ++nt) vsqr[nt] = vsq[vb0 + wn + nt * 16 + tx];
#pragma unroll
    for (int mt = 0; mt < 4; ++mt) {
#pragma unroll
        for (int r = 0; r < 4; ++r) {
            const int q_local = wq + mt * 16 + quad * 4 + r;
            ull best = ~0ull;
#pragma unroll
            for (int nt = 0; nt < 4; ++nt) {
                const float score = fmaf(-2.0f, acc[mt][nt][r], vsqr[nt]);
                const unsigned idx = (unsigned)(vb0 + wn + nt * 16 + tx);
                const ull key = pack_key(score, idx);
                best = best < key ? best : key;
            }
#pragma unroll
            for (int off = 8; off; off >>= 1) {
                const ull o = shfl_xor_u64_w16(best, off);
                best = best < o ? best : o;
            }
            if (tx == 0) red[q_local][wn >> 6] = best;
        }
    }
    __syncthreads();

    if (tid < QT) {
        const ull k0 = red[tid][0];
        const ull k1 = red[tid][1];
        const ull x  = k0 < k1 ? k0 : k1;
        const int qg_ = qb0 + tid;
        const ull old = atomicMin(&keys1[qg_], x);
        const ull loser = (x < old) ? old : x;
        if (loser != ~0ull) atomicMin(&keys2[qg_], loser);
    }
}

// ---------------- Kernel C: exact fp32 rescore of approx top-2 ----------------
__global__ __launch_bounds__(256) void rescore_kernel(const float* __restrict__ q,
                                                      const float* __restrict__ v,
                                                      const ull* __restrict__ keys1,
                                                      const ull* __restrict__ keys2,
                                                      int* __restrict__ out) {
    const int qi   = blockIdx.x * 4 + (threadIdx.x >> 6);
    const int lane = threadIdx.x & 63;
    const float4 qv = *(const float4*)(q + (size_t)qi * D + lane * 4);
    ull best = ~0ull;
    ull cand[2];
    cand[0] = keys1[qi];
    cand[1] = keys2[qi];
#pragma unroll
    for (int c = 0; c < 2; ++c) {
        if (cand[c] == ~0ull) continue;
        const unsigned idx = (unsigned)cand[c];
        const float4 vv = *(const float4*)(v + (size_t)idx * D + lane * 4);
        float s1 = vv.x * vv.x + vv.y * vv.y + vv.z * vv.z + vv.w * vv.w;
        float s2 = qv.x * vv.x + qv.y * vv.y + qv.z * vv.z + qv.w * vv.w;
#pragma unroll
        for (int off = 32; off; off >>= 1) {
            s1 += __shfl_xor(s1, off, 64);
            s2 += __shfl_xor(s2, off, 64);
        }
        const float dist = fmaf(-2.0f, s2, s1);
        const ull key = pack_key(dist, idx);
        best = best < key ? best : key;
    }
    if (lane == 0) out[qi] = (int)(unsigned)(best & 0xFFFFFFFFull);
}

extern "C" void kernel_launch(void* const* d_in, const int* in_sizes, int n_in,
                              void* d_out, int out_size, void* d_ws, size_t ws_size,
                              hipStream_t stream) {
    const float* q = (const float*)d_in[0];
    const float* v = (const float*)d_in[1];
    int* out = (int*)d_out;

    char* ws = (char*)d_ws;
    float* vsq = (float*)ws;                 ws += (size_t)N * sizeof(float);
    ull* keys1 = (ull*)ws;                   ws += (size_t)2 * M * sizeof(ull);
    ull* keys2 = keys1 + M;

    const size_t need = (size_t)N * 4 + 2ull * M * 8
                      + 2ull * M * D * 2 + 2ull * (size_t)N * D * 2;

    if (ws_size >= need) {
        short* qhi = (short*)ws;             ws += (size_t)M * D * 2;
        short* qlo = (short*)ws;             ws += (size_t)M * D * 2;
        short* vhi = (short*)ws;             ws += (size_t)N * D * 2;
        short* vlo = (short*)ws;

        convert_v_kernel<<<(N * (size_t)D / 8) / 256, 256, 0, stream>>>(v, vhi, vlo, vsq);
        convert_q_kernel<<<(M * (size_t)D / 8) / 256, 256, 0, stream>>>(q, qhi, qlo, keys1);
        dim3 grid(N / NT, M / QT);
        dist_argmin_fast<<<grid, 256, 0, stream>>>(qhi, qlo, vhi, vlo, vsq, keys1, keys2);
    } else {
        vsq_init_kernel<<<N / 4, 256, 0, stream>>>(v, vsq, keys1);
        dim3 grid(N / NT, M / QT);
        dist_argmin_conv<<<grid, 256, 0, stream>>>(q, v, vsq, keys1, keys2);
    }

    rescore_kernel<<<M / 4, 256, 0, stream>>>(q, v, keys1, keys2, out);
}

// Round 4
// 527.519 us; speedup vs baseline: 3.5581x; 1.5142x over previous
//
#include <hip/hip_runtime.h>
#include <hip/hip_bf16.h>

#define M 2048
#define N 131072
#define D 256

#define QT 128
#define NT 128
#define KC 32

typedef __attribute__((ext_vector_type(8))) _Float16 half8;  // 8 f16 (4 VGPRs)
typedef __attribute__((ext_vector_type(8))) short short8;
typedef __attribute__((ext_vector_type(4))) float f32x4;     // MFMA acc
typedef unsigned long long ull;

__device__ __forceinline__ ull pack_key(float score, unsigned idx) {
    unsigned u = __float_as_uint(score);
    u = (u & 0x80000000u) ? ~u : (u | 0x80000000u);   // monotonic total order
    return ((ull)u << 32) | idx;
}
__device__ __forceinline__ ull shfl_xor_u64_w16(ull x, int mask) {
    unsigned lo = (unsigned)x, hi = (unsigned)(x >> 32);
    lo = (unsigned)__shfl_xor((int)lo, mask, 16);
    hi = (unsigned)__shfl_xor((int)hi, mask, 16);
    return ((ull)hi << 32) | lo;
}
// async global->LDS, 16B per lane; lds base wave-uniform, lane i lands at +16*i
__device__ __forceinline__ void async16(const void* g, void* l) {
    __builtin_amdgcn_global_load_lds((const __attribute__((address_space(1))) void*)g,
                                     (__attribute__((address_space(3))) void*)l, 16, 0, 0);
}

// ---------------- Kernel A1: V -> f16 + vsq (fp32, V read once) ----------------
__global__ __launch_bounds__(256) void convert_v_kernel(const float* __restrict__ v,
                                                        short* __restrict__ vh,
                                                        float* __restrict__ vsq) {
    const size_t t = (size_t)blockIdx.x * 256 + threadIdx.x;   // N*D/8 threads
    const float* src = v + t * 8;
    float tmp[8] __attribute__((aligned(16)));
    *(float4*)&tmp[0] = *(const float4*)src;
    *(float4*)&tmp[4] = *(const float4*)(src + 4);
    half8 h;
    float s = 0.f;
#pragma unroll
    for (int e = 0; e < 8; ++e) {
        h[e] = (_Float16)tmp[e];          // RNE f32->f16
        s += tmp[e] * tmp[e];             // exact-ish fp32 ||v||^2
    }
    *(short8*)(vh + t * 8) = *(short8*)&h;
#pragma unroll
    for (int off = 16; off; off >>= 1) s += __shfl_xor(s, off, 32);   // 32 threads/row
    if ((threadIdx.x & 31) == 0) vsq[t >> 5] = s;
}

// ---------------- Kernel A2: Q -> f16 + key init ----------------
__global__ __launch_bounds__(256) void convert_q_kernel(const float* __restrict__ q,
                                                        short* __restrict__ qh,
                                                        ull* __restrict__ keys) {
    const size_t t = (size_t)blockIdx.x * 256 + threadIdx.x;   // M*D/8 threads
    const float* src = q + t * 8;
    float tmp[8] __attribute__((aligned(16)));
    *(float4*)&tmp[0] = *(const float4*)src;
    *(float4*)&tmp[4] = *(const float4*)(src + 4);
    half8 h;
#pragma unroll
    for (int e = 0; e < 8; ++e) h[e] = (_Float16)tmp[e];
    *(short8*)(qh + t * 8) = *(short8*)&h;
    if (blockIdx.x == 0) {
        for (int i = threadIdx.x; i < 2 * M; i += 256) keys[i] = ~0ull;
    }
}

// ---------------- Kernel B: single-pass f16 MFMA + block-best top-2 insert ----------------
__global__ __launch_bounds__(256) void dist_argmin_f16(const short* __restrict__ qh,
                                                       const short* __restrict__ vh,
                                                       const float* __restrict__ vsq,
                                                       ull* __restrict__ keys1,
                                                       ull* __restrict__ keys2) {
    __shared__ __align__(16) short sQ[QT * KC];   // f16 tile, row-major [row][KC], 64B rows
    __shared__ __align__(16) short sV[NT * KC];
    __shared__ ull red[QT][2];

    const int tid  = threadIdx.x;
    const int lane = tid & 63;
    const int w    = tid >> 6;
    const int wq   = (w >> 1) * 64;
    const int wn   = (w & 1) * 64;
    const int tx   = lane & 15;
    const int quad = lane >> 4;

    const int qb0 = blockIdx.y * QT;
    const int vb0 = blockIdx.x * NT;

    f32x4 acc[4][4];
#pragma unroll
    for (int i = 0; i < 4; ++i)
#pragma unroll
        for (int j = 0; j < 4; ++j) acc[i][j] = (f32x4){0.f, 0.f, 0.f, 0.f};

    // DMA staging: wave w stages rows [w*32, w*32+32); lane i -> row w*32+(i>>2), col (i&3)*8
    const int  srow = w * 32 + (lane >> 2);
    const int  scol = (lane & 3) * 8;
    const size_t qg = (size_t)(qb0 + srow) * D + scol;
    const size_t vg = (size_t)(vb0 + srow) * D + scol;
    const int  l0   = (w * 32) * KC;          // wave-uniform LDS short-offsets
    const int  l1   = (w * 32 + 16) * KC;

    for (int dc = 0; dc < D; dc += KC) {
        __syncthreads();
        async16(qh + qg + dc,          sQ + l0);
        async16(qh + qg + 16 * D + dc, sQ + l1);
        async16(vh + vg + dc,          sV + l0);
        async16(vh + vg + 16 * D + dc, sV + l1);
        __syncthreads();

        half8 a[4];
#pragma unroll
        for (int mt = 0; mt < 4; ++mt)
            a[mt] = *(const half8*)(sQ + (wq + mt * 16 + tx) * KC + quad * 8);
#pragma unroll
        for (int nt = 0; nt < 4; ++nt) {
            const half8 b = *(const half8*)(sV + (wn + nt * 16 + tx) * KC + quad * 8);
#pragma unroll
            for (int mt = 0; mt < 4; ++mt)
                acc[mt][nt] = __builtin_amdgcn_mfma_f32_16x16x32_f16(a[mt], b, acc[mt][nt], 0, 0, 0);
        }
    }

    float vsqr[4];
#pragma unroll
    for (int nt = 0; nt < 4; ++nt) vsqr[nt] = vsq[vb0 + wn + nt * 16 + tx];

#pragma unroll
    for (int mt = 0; mt < 4; ++mt) {
#pragma unroll
        for (int r = 0; r < 4; ++r) {
            const int q_local = wq + mt * 16 + quad * 4 + r;
            ull best = ~0ull;
#pragma unroll
            for (int nt = 0; nt < 4; ++nt) {
                const float score = fmaf(-2.0f, acc[mt][nt][r], vsqr[nt]);
                const unsigned idx = (unsigned)(vb0 + wn + nt * 16 + tx);
                const ull key = pack_key(score, idx);
                best = best < key ? best : key;
            }
#pragma unroll
            for (int off = 8; off; off >>= 1) {
                const ull o = shfl_xor_u64_w16(best, off);
                best = best < o ? best : o;
            }
            if (tx == 0) red[q_local][wn >> 6] = best;
        }
    }
    __syncthreads();

    if (tid < QT) {
        const ull k0 = red[tid][0];
        const ull k1 = red[tid][1];
        const ull x  = k0 < k1 ? k0 : k1;      // block-best for this query
        const int qg_ = qb0 + tid;
        const ull old = atomicMin(&keys1[qg_], x);
        const ull loser = (x < old) ? old : x;
        if (loser != ~0ull) atomicMin(&keys2[qg_], loser);
    }
}

// ---------------- Kernel C: exact fp32 rescore of approx top-2 ----------------
__global__ __launch_bounds__(256) void rescore_kernel(const float* __restrict__ q,
                                                      const float* __restrict__ v,
                                                      const ull* __restrict__ keys1,
                                                      const ull* __restrict__ keys2,
                                                      int* __restrict__ out) {
    const int qi   = blockIdx.x * 4 + (threadIdx.x >> 6);
    const int lane = threadIdx.x & 63;
    const float4 qv = *(const float4*)(q + (size_t)qi * D + lane * 4);
    ull best = ~0ull;
    ull cand[2];
    cand[0] = keys1[qi];
    cand[1] = keys2[qi];
#pragma unroll
    for (int c = 0; c < 2; ++c) {
        if (cand[c] == ~0ull) continue;
        const unsigned idx = (unsigned)cand[c];
        const float4 vv = *(const float4*)(v + (size_t)idx * D + lane * 4);
        float s1 = vv.x * vv.x + vv.y * vv.y + vv.z * vv.z + vv.w * vv.w;   // ||v||^2
        float s2 = qv.x * vv.x + qv.y * vv.y + qv.z * vv.z + qv.w * vv.w;   // q.v
#pragma unroll
        for (int off = 32; off; off >>= 1) {
            s1 += __shfl_xor(s1, off, 64);
            s2 += __shfl_xor(s2, off, 64);
        }
        const float dist = fmaf(-2.0f, s2, s1);   // exact fp32 score (sans ||q||^2)
        const ull key = pack_key(dist, idx);
        best = best < key ? best : key;
    }
    if (lane == 0) out[qi] = (int)(unsigned)(best & 0xFFFFFFFFull);
}

extern "C" void kernel_launch(void* const* d_in, const int* in_sizes, int n_in,
                              void* d_out, int out_size, void* d_ws, size_t ws_size,
                              hipStream_t stream) {
    const float* q = (const float*)d_in[0];
    const float* v = (const float*)d_in[1];
    int* out = (int*)d_out;

    char* ws = (char*)d_ws;
    float* vsq = (float*)ws;                 ws += (size_t)N * sizeof(float);
    ull* keys1 = (ull*)ws;                   ws += (size_t)2 * M * sizeof(ull);
    ull* keys2 = keys1 + M;
    short* qh = (short*)ws;                  ws += (size_t)M * D * 2;
    short* vh = (short*)ws;

    // ws need: 0.5 MB vsq + 32 KB keys + 1 MB qh + 64 MB vh  (<< round-3's 136 MB, which fit)
    convert_v_kernel<<<((size_t)N * D / 8) / 256, 256, 0, stream>>>(v, vh, vsq);
    convert_q_kernel<<<((size_t)M * D / 8) / 256, 256, 0, stream>>>(q, qh, keys1);

    dim3 grid(N / NT, M / QT);   // (1024, 16)
    dist_argmin_f16<<<grid, 256, 0, stream>>>(qh, vh, vsq, keys1, keys2);

    rescore_kernel<<<M / 4, 256, 0, stream>>>(q, v, keys1, keys2, out);
}